// Round 6
// baseline (333.170 us; speedup 1.0000x reference)
//
#include <hip/hip_runtime.h>
#include <math.h>

#define SCALE_ 0.08838834764831845f   // 1/sqrt(128)
#define MINV_  (-3.4028234663852886e38f)

typedef __bf16 bf16;
typedef bf16  bf16x4 __attribute__((ext_vector_type(4)));
typedef bf16  bf16x8 __attribute__((ext_vector_type(8)));
typedef float f32x4  __attribute__((ext_vector_type(4)));
typedef float f32x16 __attribute__((ext_vector_type(16)));
typedef float float4v __attribute__((ext_vector_type(4)));

#define LD8(p) (*(const bf16x8*)(p))

__device__ __forceinline__ f32x4 mfma16(bf16x8 a, bf16x8 b, f32x4 c) {
    return __builtin_amdgcn_mfma_f32_16x16x32_bf16(a, b, c, 0, 0, 0);
}
__device__ __forceinline__ f32x16 mfma32(bf16x8 a, bf16x8 b, f32x16 c) {
    return __builtin_amdgcn_mfma_f32_32x32x16_bf16(a, b, c, 0, 0, 0);
}

typedef const __attribute__((address_space(1))) void* gas_t;
typedef __attribute__((address_space(3))) void* sas_t;
__device__ __forceinline__ void gload_lds16(const void* g, void* l) {
    __builtin_amdgcn_global_load_lds((gas_t)g, (sas_t)l, 16, 0, 0);
}

// ---------------- prep kernels ----------------

__global__ __launch_bounds__(256) void cast_hidden_kernel(const float* __restrict__ X, bf16* __restrict__ Y)
{
    int i = (blockIdx.x * 256 + threadIdx.x) * 4;
    float4v v = *(const float4v*)(X + i);
    bf16x4 o; o.x = (bf16)v.x; o.y = (bf16)v.y; o.z = (bf16)v.z; o.w = (bf16)v.w;
    *(bf16x4*)(Y + i) = o;
}

// BT[n][k] = W[k][src(n)]; qmap: src = (n>>7)*384 + (n&127) (q columns of Wqkv), else src=n (Wo)
__global__ __launch_bounds__(256) void transpose_cast_kernel(const float* __restrict__ W, bf16* __restrict__ BT,
                                                             int srcStride, int qmap)
{
    __shared__ float tile[32][33];
    int k0 = blockIdx.x * 32, n0 = blockIdx.y * 32;
    int c = threadIdx.x & 31, r = threadIdx.x >> 5;   // r in 0..7
    int n = n0 + c;
    int src = qmap ? ((n >> 7) * 384 + (n & 127)) : n;
    #pragma unroll
    for (int rr = 0; rr < 32; rr += 8)
        tile[r + rr][c] = W[(size_t)(k0 + r + rr) * srcStride + src];
    __syncthreads();
    #pragma unroll
    for (int rr = 0; rr < 32; rr += 8)
        BT[(size_t)(n0 + r + rr) * 2048 + k0 + c] = (bf16)tile[c][r + rr];
}

// rows 2048..2303 of BT1: head-averaged k/v weight columns. Coalesced: thread=j, 1KB row segments.
__global__ __launch_bounds__(256) void bt1_kv_kernel(const float* __restrict__ Wqkv, bf16* __restrict__ BT1)
{
    int k0 = blockIdx.x * 16;
    int j = threadIdx.x;            // 0..255
    float acc[16];
    #pragma unroll
    for (int k = 0; k < 16; k++) acc[k] = 0.f;
    for (int h = 0; h < 16; h++) {
        #pragma unroll
        for (int k = 0; k < 16; k++)
            acc[k] += Wqkv[(size_t)(k0 + k) * 6144 + h * 384 + 128 + j];
    }
    #pragma unroll
    for (int k = 0; k < 16; k++)
        BT1[(size_t)(2048 + j) * 2048 + k0 + k] = (bf16)(acc[k] * 0.0625f);
}

__global__ void bias1_kernel(const float* __restrict__ bqkv, float* __restrict__ bias1)
{
    int c = blockIdx.x * 256 + threadIdx.x;
    if (c >= 2304) return;
    if (c < 2048) bias1[c] = bqkv[(c >> 7) * 384 + (c & 127)];
    else {
        int j = c - 2048; float s = 0.f;
        for (int h = 0; h < 16; h++) s += bqkv[h * 384 + 128 + j];
        bias1[c] = s * 0.0625f;
    }
}

// ---------------- GEMM: 128x64 tile, 4 waves (wave 32x64), BK=64, mfma32 ----------------
// global_load_lds width-16 staging with XOR swizzle on gather side; 4+ blocks/CU for
// staging-latency overlap (the R5 limiter). 1-D grid with 4(m) x n supertile swizzle.
template<int OUT_BF16>
__global__ __launch_bounds__(256, 4) void gemm_kernel(const bf16* __restrict__ A, const bf16* __restrict__ BT,
                                                      const float* __restrict__ bias, void* __restrict__ Cout,
                                                      int N, int K, int nTiles, int nbTot)
{
    __shared__ __align__(16) bf16 As[128 * 64];
    __shared__ __align__(16) bf16 Bs[64 * 64];
    const int tid  = threadIdx.x;
    const int wv   = tid >> 6, lane = tid & 63, l32 = lane & 31, half = lane >> 5;

    // swizzled tile decode: 4 m-tiles x nTiles per supergroup, m fastest then n
    int b = blockIdx.x;
    int group = b / (4 * nTiles), rem = b % (4 * nTiles);
    int mi = group * 4 + (rem & 3), ni = rem >> 2;
    const int m0 = mi * 128, n0 = ni * 64;

    // staging geometry: 24 chunks (A:0..15, B:16..23); wave wv issues j=0..5 -> ci = wv*6+j
    int ciS[6], rowS[6], colS[6];
    #pragma unroll
    for (int j = 0; j < 6; j++) {
        int ci = wv * 6 + j;
        ciS[j] = ci;
        int cb = (ci < 16) ? ci : (ci - 16);
        int row = cb * 8 + (lane >> 3), cp = lane & 7;
        rowS[j] = row;
        colS[j] = (cp ^ (row & 7)) * 8;
    }

    f32x16 acc[2];
    #pragma unroll
    for (int t = 0; t < 2; t++)
        #pragma unroll
        for (int r = 0; r < 16; r++) acc[t][r] = 0.f;

    for (int kk = 0; kk < K; kk += 64) {
        __syncthreads();
        #pragma unroll
        for (int j = 0; j < 6; j++) {
            int ci = ciS[j];
            if (ci < 16) gload_lds16(A  + (size_t)(m0 + rowS[j]) * K + kk + colS[j], &As[ci * 512]);
            else         gload_lds16(BT + (size_t)(n0 + rowS[j]) * K + kk + colS[j], &Bs[(ci - 16) * 512]);
        }
        __syncthreads();

        bf16x8 af[4], bfr[2][4];
        {
            int row = wv * 32 + l32;
            #pragma unroll
            for (int k16 = 0; k16 < 4; k16++) {
                int lc = k16 * 2 + half;
                af[k16] = LD8(&As[row * 64 + ((lc ^ (row & 7)) * 8)]);
            }
        }
        #pragma unroll
        for (int nt = 0; nt < 2; nt++) {
            int row = nt * 32 + l32;
            #pragma unroll
            for (int k16 = 0; k16 < 4; k16++) {
                int lc = k16 * 2 + half;
                bfr[nt][k16] = LD8(&Bs[row * 64 + ((lc ^ (row & 7)) * 8)]);
            }
        }
        #pragma unroll
        for (int k16 = 0; k16 < 4; k16++)
            #pragma unroll
            for (int nt = 0; nt < 2; nt++)
                acc[nt] = mfma32(af[k16], bfr[nt][k16], acc[nt]);
    }

    #pragma unroll
    for (int nt = 0; nt < 2; nt++) {
        int n = n0 + nt * 32 + l32;
        float bn = bias[n];
        #pragma unroll
        for (int r = 0; r < 16; r++) {
            int m = m0 + wv * 32 + (r & 3) + 8 * (r >> 2) + 4 * half;
            float v = acc[nt][r] + bn;
            if (OUT_BF16) ((bf16*)Cout)[(size_t)m * N + n] = (bf16)v;
            else          ((float*)Cout)[(size_t)m * N + n] = v;
        }
    }
}

// ---------------- rotary (in-place on C1 bf16): q (16 heads) + k_mean, first 32 dims ----------------
__global__ __launch_bounds__(320) void rotary_kernel(bf16* __restrict__ C1)
{
    int row = blockIdx.x;          // b*2048 + s
    int s = row & 2047;
    int t = threadIdx.x;
    if (t >= 272) return;          // 17 groups (16 q heads + k_mean) x 16 dim-pairs
    int g = t >> 4, dd = t & 15;
    bf16* ptr = C1 + (size_t)row * 2304 + (g < 16 ? g * 128 : 2048);
    float x0 = (float)ptr[dd], x1 = (float)ptr[dd + 16];
    const float L = 0.575646273248511f;  // ln(10000)/16
    float inv = __expf(-L * (float)dd);
    float ang = (float)s * inv;
    float c, si;
    __sincosf(ang, &si, &c);
    ptr[dd]      = (bf16)(x0 * c - x1 * si);
    ptr[dd + 16] = (bf16)(x1 * c + x0 * si);
}

// ---------------- vmT[b][d][s] = v_mean transposed ----------------
__global__ __launch_bounds__(256) void build_vmT_kernel(const bf16* __restrict__ C1, bf16* __restrict__ vmT)
{
    __shared__ float tile[32][33];
    int b = blockIdx.z;
    int s0 = blockIdx.x * 32, d0 = blockIdx.y * 32;
    int c = threadIdx.x & 31, r = threadIdx.x >> 5;
    #pragma unroll
    for (int rr = 0; rr < 32; rr += 8)
        tile[r + rr][c] = (float)C1[(size_t)(b * 2048 + s0 + r + rr) * 2304 + 2176 + d0 + c];
    __syncthreads();
    #pragma unroll
    for (int rr = 0; rr < 32; rr += 8)
        vmT[(size_t)(b * 128 + d0 + r + rr) * 2048 + s0 + c] = (bf16)tile[c][r + rr];
}

// ---------------- pretile K/V into MFMA fragment order; blockIdx.x==32 -> gathered global chunk ----------------
__global__ __launch_bounds__(256) void pretile_kernel(const bf16* __restrict__ C1, const bf16* __restrict__ vmT,
                                                      const int* __restrict__ gidx,
                                                      bf16* __restrict__ KF, bf16* __restrict__ VF)
{
    int c = blockIdx.x, b = blockIdx.y;
    bool isGlob = (c == 32);
    for (int i = 0; i < 8; i++) {
        int sid = threadIdx.x + i * 256;     // 0..2047
        int lane = sid & 63, fi = (sid >> 6) & 15;
        int l16 = lane & 15, quad = lane >> 4;
        if (sid < 1024) {
            int t = fi >> 2, ks = fi & 3;
            int pos = isGlob ? gidx[b * 64 + t * 16 + l16] : (c * 64 + t * 16 + l16);
            const bf16* src = C1 + (size_t)(b * 2048 + pos) * 2304 + 2048 + ks * 32 + quad * 8;
            *(bf16x8*)&KF[((size_t)(b * 33 + c) * 16 + fi) * 512 + lane * 8] = LD8(src);
        } else {
            int dt = fi >> 1, ks2 = fi & 1;
            int d = dt * 16 + l16;
            if (isGlob) {
                bf16 tmp[8];
                #pragma unroll
                for (int j = 0; j < 8; j++) {
                    int pos = gidx[b * 64 + ks2 * 32 + quad * 8 + j];
                    tmp[j] = vmT[(size_t)(b * 128 + d) * 2048 + pos];
                }
                #pragma unroll
                for (int j = 0; j < 8; j++)
                    VF[((size_t)(b * 33 + 32) * 16 + fi) * 512 + lane * 8 + j] = tmp[j];
            } else {
                const bf16* src = vmT + (size_t)(b * 128 + d) * 2048 + c * 64 + ks2 * 32 + quad * 8;
                *(bf16x8*)&VF[((size_t)(b * 33 + c) * 16 + fi) * 512 + lane * 8] = LD8(src);
            }
        }
    }
}

#define PSTRIDE 88

// ---------------- attention, first WIN=256 queries (causal): wave-autonomous, pretiled frags ----------------
__global__ __launch_bounds__(256) void attn0_kernel(const bf16* __restrict__ C1, const bf16* __restrict__ KF,
                                                    const bf16* __restrict__ VF, const float* __restrict__ mask,
                                                    bf16* __restrict__ attn)
{
    const int bx = blockIdx.x, h = blockIdx.y, b = blockIdx.z;
    const int tid = threadIdx.x, wv = tid >> 6, lane = tid & 63, quad = lane >> 4, l16 = lane & 15;
    const int q0 = (bx * 4 + wv) * 16;

    __shared__ __align__(16) bf16 Ps[4 * 16 * PSTRIDE];
    bf16* Pw = &Ps[wv * (16 * PSTRIDE)];

    bf16x8 af[4];
    const bf16* qbase = C1 + (size_t)(b * 2048 + q0 + l16) * 2304 + h * 128;
    #pragma unroll
    for (int ks = 0; ks < 4; ks++) af[ks] = LD8(qbase + ks * 32 + quad * 8);

    f32x4 m_run = (f32x4){MINV_, MINV_, MINV_, MINV_};
    f32x4 l_run = (f32x4){0.f, 0.f, 0.f, 0.f};
    f32x4 O[8];
    #pragma unroll
    for (int dt = 0; dt < 8; dt++) O[dt] = (f32x4){0.f, 0.f, 0.f, 0.f};

    for (int c = 0; c <= bx; c++) {
        const bf16* KFc = KF + ((size_t)(b * 33 + c) * 16) * 512;
        const bf16* VFc = VF + ((size_t)(b * 33 + c) * 16) * 512;

        f32x4 acc[4];
        #pragma unroll
        for (int t = 0; t < 4; t++) acc[t] = (f32x4){0.f, 0.f, 0.f, 0.f};
        #pragma unroll
        for (int t = 0; t < 4; t++)
            #pragma unroll
            for (int ks = 0; ks < 4; ks++)
                acc[t] = mfma16(af[ks], LD8(KFc + (size_t)(t * 4 + ks) * 512 + lane * 8), acc[t]);

        float sv[4][4];
        #pragma unroll
        for (int t = 0; t < 4; t++) {
            int key = c * 64 + t * 16 + l16;
            float addv = mask[b * 2048 + key];
            #pragma unroll
            for (int r = 0; r < 4; r++) {
                int q = q0 + quad * 4 + r;
                sv[t][r] = (key <= q) ? (acc[t][r] * SCALE_ + addv) : MINV_;
            }
        }

        f32x4 cm;
        #pragma unroll
        for (int r = 0; r < 4; r++) cm[r] = fmaxf(fmaxf(sv[0][r], sv[1][r]), fmaxf(sv[2][r], sv[3][r]));
        #pragma unroll
        for (int ms = 1; ms < 16; ms <<= 1)
            #pragma unroll
            for (int r = 0; r < 4; r++) cm[r] = fmaxf(cm[r], __shfl_xor(cm[r], ms, 64));

        f32x4 nm, alpha;
        #pragma unroll
        for (int r = 0; r < 4; r++) { nm[r] = fmaxf(m_run[r], cm[r]); alpha[r] = __expf(m_run[r] - nm[r]); }

        float pv[4][4];
        f32x4 cs = (f32x4){0.f, 0.f, 0.f, 0.f};
        #pragma unroll
        for (int t = 0; t < 4; t++)
            #pragma unroll
            for (int r = 0; r < 4; r++) {
                pv[t][r] = __expf(sv[t][r] - nm[r]);   // MINV_ underflows to 0
                cs[r] += pv[t][r];
            }
        #pragma unroll
        for (int ms = 1; ms < 16; ms <<= 1)
            #pragma unroll
            for (int r = 0; r < 4; r++) cs[r] += __shfl_xor(cs[r], ms, 64);

        m_run = nm;
        #pragma unroll
        for (int r = 0; r < 4; r++) l_run[r] = l_run[r] * alpha[r] + cs[r];
        #pragma unroll
        for (int dt = 0; dt < 8; dt++)
            #pragma unroll
            for (int r = 0; r < 4; r++) O[dt][r] *= alpha[r];

        #pragma unroll
        for (int t = 0; t < 4; t++)
            #pragma unroll
            for (int r = 0; r < 4; r++)
                Pw[(quad * 4 + r) * PSTRIDE + t * 16 + l16] = (bf16)pv[t][r];
        bf16x8 pa0 = LD8(&Pw[l16 * PSTRIDE + quad * 8]);
        bf16x8 pa1 = LD8(&Pw[l16 * PSTRIDE + 32 + quad * 8]);

        #pragma unroll
        for (int dt = 0; dt < 8; dt++) {
            O[dt] = mfma16(pa0, LD8(VFc + (size_t)(dt * 2 + 0) * 512 + lane * 8), O[dt]);
            O[dt] = mfma16(pa1, LD8(VFc + (size_t)(dt * 2 + 1) * 512 + lane * 8), O[dt]);
        }
    }

    f32x4 invl;
    #pragma unroll
    for (int r = 0; r < 4; r++) invl[r] = 1.0f / l_run[r];
    #pragma unroll
    for (int dt = 0; dt < 8; dt++)
        #pragma unroll
        for (int r = 0; r < 4; r++) {
            int q = q0 + quad * 4 + r;
            attn[(size_t)(b * 2048 + q) * 2048 + h * 128 + dt * 16 + l16] = (bf16)(O[dt][r] * invl[r]);
        }
}

// ---------------- attention steps v3: barrier-free, wave-autonomous, pretiled frags ----------------
__global__ __launch_bounds__(256) void attn_steps3_kernel(const bf16* __restrict__ C1, const bf16* __restrict__ KF,
                                                          const bf16* __restrict__ VF, const float* __restrict__ mask,
                                                          const int* __restrict__ gidx, bf16* __restrict__ attn)
{
    const int sb = blockIdx.x, b = blockIdx.y;
    const int tid = threadIdx.x, wv = tid >> 6, lane = tid & 63, quad = lane >> 4, l16 = lane & 15;
    const int step = sb * 4 + wv, p = 256 + step;

    __shared__ __align__(16) bf16 Ps[4 * 16 * PSTRIDE];
    bf16* Pw = &Ps[wv * (16 * PSTRIDE)];

    bf16x8 af[4];
    const bf16* qrow = C1 + (size_t)(b * 2048 + p) * 2304;
    #pragma unroll
    for (int ks = 0; ks < 4; ks++) af[ks] = LD8(qrow + l16 * 128 + ks * 32 + quad * 8);

    int gix[4];
    #pragma unroll
    for (int t = 0; t < 4; t++) gix[t] = gidx[b * 64 + t * 16 + l16];

    f32x4 m_run = (f32x4){MINV_, MINV_, MINV_, MINV_};
    f32x4 l_run = (f32x4){0.f, 0.f, 0.f, 0.f};
    f32x4 O[8];
    #pragma unroll
    for (int dt = 0; dt < 8; dt++) O[dt] = (f32x4){0.f, 0.f, 0.f, 0.f};

    const int c0 = (step + 1) >> 6;

    for (int iter = 0; iter < 6; iter++) {
        int c;
        bool isGlob = (iter == 0);
        if (isGlob) c = 32;
        else { c = c0 + iter - 1; if (c > 31) break; }

        const bf16* KFc = KF + ((size_t)(b * 33 + c) * 16) * 512;
        const bf16* VFc = VF + ((size_t)(b * 33 + c) * 16) * 512;

        f32x4 acc[4];
        #pragma unroll
        for (int t = 0; t < 4; t++) acc[t] = (f32x4){0.f, 0.f, 0.f, 0.f};
        #pragma unroll
        for (int t = 0; t < 4; t++)
            #pragma unroll
            for (int ks = 0; ks < 4; ks++)
                acc[t] = mfma16(af[ks], LD8(KFc + (size_t)(t * 4 + ks) * 512 + lane * 8), acc[t]);

        float sv[4][4];
        bool vld[4];
        #pragma unroll
        for (int t = 0; t < 4; t++) {
            float addv = 0.f;
            if (isGlob) vld[t] = gix[t] < step;
            else {
                int pos = c * 64 + t * 16 + l16;
                vld[t] = (unsigned)(pos - step - 1) < 256u;
                addv = mask[b * 2048 + pos];
            }
            #pragma unroll
            for (int r = 0; r < 4; r++) sv[t][r] = vld[t] ? (acc[t][r] * SCALE_ + addv) : MINV_;
        }

        f32x4 cm;
        #pragma unroll
        for (int r = 0; r < 4; r++) cm[r] = fmaxf(fmaxf(sv[0][r], sv[1][r]), fmaxf(sv[2][r], sv[3][r]));
        #pragma unroll
        for (int ms = 1; ms < 16; ms <<= 1)
            #pragma unroll
            for (int r = 0; r < 4; r++) cm[r] = fmaxf(cm[r], __shfl_xor(cm[r], ms, 64));

        f32x4 nm, alpha;
        #pragma unroll
        for (int r = 0; r < 4; r++) { nm[r] = fmaxf(m_run[r], cm[r]); alpha[r] = __expf(m_run[r] - nm[r]); }

        float pv[4][4];
        f32x4 cs = (f32x4){0.f, 0.f, 0.f, 0.f};
        #pragma unroll
        for (int t = 0; t < 4; t++)
            #pragma unroll
            for (int r = 0; r < 4; r++) {
                pv[t][r] = vld[t] ? __expf(sv[t][r] - nm[r]) : 0.f;
                cs[r] += pv[t][r];
            }
        #pragma unroll
        for (int ms = 1; ms < 16; ms <<= 1)
            #pragma unroll
            for (int r = 0; r < 4; r++) cs[r] += __shfl_xor(cs[r], ms, 64);

        m_run = nm;
        #pragma unroll
        for (int r = 0; r < 4; r++) l_run[r] = l_run[r] * alpha[r] + cs[r];
        #pragma unroll
        for (int dt = 0; dt < 8; dt++)
            #pragma unroll
            for (int r = 0; r < 4; r++) O[dt][r] *= alpha[r];

        #pragma unroll
        for (int t = 0; t < 4; t++)
            #pragma unroll
            for (int r = 0; r < 4; r++)
                Pw[(quad * 4 + r) * PSTRIDE + t * 16 + l16] = (bf16)pv[t][r];
        bf16x8 pa0 = LD8(&Pw[l16 * PSTRIDE + quad * 8]);
        bf16x8 pa1 = LD8(&Pw[l16 * PSTRIDE + 32 + quad * 8]);

        #pragma unroll
        for (int dt = 0; dt < 8; dt++) {
            O[dt] = mfma16(pa0, LD8(VFc + (size_t)(dt * 2 + 0) * 512 + lane * 8), O[dt]);
            O[dt] = mfma16(pa1, LD8(VFc + (size_t)(dt * 2 + 1) * 512 + lane * 8), O[dt]);
        }
    }

    f32x4 invl;
    #pragma unroll
    for (int r = 0; r < 4; r++) invl[r] = 1.0f / l_run[r];
    #pragma unroll
    for (int dt = 0; dt < 8; dt++)
        #pragma unroll
        for (int r = 0; r < 4; r++) {
            int h = quad * 4 + r;
            attn[(size_t)(b * 2048 + p) * 2048 + h * 128 + dt * 16 + l16] = (bf16)(O[dt][r] * invl[r]);
        }
}

// ---------------- launch ----------------
extern "C" void kernel_launch(void* const* d_in, const int* in_sizes, int n_in,
                              void* d_out, int out_size, void* d_ws, size_t ws_size,
                              hipStream_t stream)
{
    const float* hidden = (const float*)d_in[0];
    const float* amask  = (const float*)d_in[1];
    const int*   gidx   = (const int*)d_in[2];
    const float* Wqkv   = (const float*)d_in[3];
    const float* bqkv   = (const float*)d_in[4];
    const float* Wo     = (const float*)d_in[5];
    const float* bo     = (const float*)d_in[6];

    char* ws = (char*)d_ws;
    size_t off = 0;
    auto take = [&](size_t bytes) -> char* {
        char* p = ws + off;
        off = (off + bytes + 255) & ~(size_t)255;
        return p;
    };
    bf16*  A16   = (bf16*)take(4096ull * 2048 * 2);   // hidden, bf16
    bf16*  BT1   = (bf16*)take(2304ull * 2048 * 2);   // [q cols | k-avg | v-avg]^T
    bf16*  BT2   = (bf16*)take(2048ull * 2048 * 2);   // Wo^T
    bf16*  C1    = (bf16*)take(4096ull * 2304 * 2);   // q(2048) | k_mean(128) | v_mean(128)
    bf16*  vmT   = (bf16*)take(2ull * 128 * 2048 * 2);
    bf16*  KF    = (bf16*)take(2ull * 33 * 16 * 512 * 2);
    bf16*  VF    = (bf16*)take(2ull * 33 * 16 * 512 * 2);
    bf16*  attnb = (bf16*)take(4096ull * 2048 * 2);
    float* bias1 = (float*)take(2304 * 4);

    cast_hidden_kernel<<<8192, 256, 0, stream>>>(hidden, A16);
    transpose_cast_kernel<<<dim3(64, 64), 256, 0, stream>>>(Wqkv, BT1, 6144, 1);
    bt1_kv_kernel<<<128, 256, 0, stream>>>(Wqkv, BT1);
    bias1_kernel<<<9, 256, 0, stream>>>(bqkv, bias1);
    transpose_cast_kernel<<<dim3(64, 64), 256, 0, stream>>>(Wo, BT2, 2048, 0);

    // gemm1: M=4096 (32 m-tiles), N=2304 (36 n-tiles) -> 1152 blocks
    gemm_kernel<1><<<1152, 256, 0, stream>>>(A16, BT1, bias1, (void*)C1, 2304, 2048, 36, 1152);

    rotary_kernel<<<4096, 320, 0, stream>>>(C1);
    build_vmT_kernel<<<dim3(64, 4, 2), 256, 0, stream>>>(C1, vmT);
    pretile_kernel<<<dim3(33, 2), 256, 0, stream>>>(C1, vmT, gidx, KF, VF);

    attn0_kernel<<<dim3(4, 16, 2), 256, 0, stream>>>(C1, KF, VF, amask, attnb);
    attn_steps3_kernel<<<dim3(448, 2), 256, 0, stream>>>(C1, KF, VF, amask, gidx, attnb);

    // gemm2: M=4096 (32 m-tiles), N=2048 (32 n-tiles) -> 1024 blocks
    gemm_kernel<0><<<1024, 256, 0, stream>>>(attnb, BT2, bo, d_out, 2048, 2048, 32, 1024);

    (void)in_sizes; (void)n_in; (void)out_size; (void)ws_size;
}